// Round 11
// baseline (223.993 us; speedup 1.0000x reference)
//
#include <hip/hip_runtime.h>

// Problem constants
constexpr int Bn = 32, Tn = 8, Cn = 1024, Sn = 4096, Hn = 16, HDn = 64;
constexpr int CHUNK = 64, NCHUNK = 64;  // 64-row chunks (pacc/merge granularity)
constexpr int KSPLIT = 4;               // K-split for the 256x1024x1024 GEMMs
constexpr float SCALE = 0.125f;         // 1/sqrt(64)

// Workspace layout (in floats)
constexpr size_t PROJ_PART = (size_t)Bn * Tn * Cn;          // 262144
constexpr size_t QP_OFF = 0;
constexpr size_t KP_OFF = QP_OFF + KSPLIT * PROJ_PART;
constexpr size_t VP_OFF = KP_OFF + KSPLIT * PROJ_PART;
constexpr size_t PACC_OFF = VP_OFF + KSPLIT * PROJ_PART;
constexpr size_t PACC_SZ = (size_t)NCHUNK * Bn * Hn * Tn * HDn;  // 16.8M floats
constexpr size_t PL_OFF = PACC_OFF + PACC_SZ;
constexpr size_t PL_SZ = (size_t)NCHUNK * Bn * Hn * Tn;
constexpr size_t AW_OFF = PL_OFF + PL_SZ;
constexpr size_t AW_SZ = PROJ_PART;
constexpr size_t OP_OFF = AW_OFF + AW_SZ;
constexpr size_t OP_SZ = (size_t)KSPLIT * PROJ_PART;
constexpr size_t QR_OFF = OP_OFF + OP_SZ;                   // reduced q (pre-scaled)
constexpr size_t KN_OFF = QR_OFF + PROJ_PART;               // reduced k_new
constexpr size_t VN_OFF = KN_OFF + PROJ_PART;               // reduced v_new

typedef __attribute__((address_space(3))) unsigned int lds_uint;
typedef const __attribute__((address_space(1))) unsigned int glb_uint;

__device__ __forceinline__ void gload_lds16(const float* g, float* l) {
    __builtin_amdgcn_global_load_lds((glb_uint*)g, (lds_uint*)l, 16, 0, 0);
}

// ---------------- GEMM: Y_partial[sigma] = X(256xK-slice) @ W^T ----------------
__device__ __forceinline__ void gemm_body(const float* __restrict__ X,
                                          const float* __restrict__ W,
                                          float* __restrict__ Opart,
                                          int sigma, int jblk, int iblk) {
    __shared__ float wl[64][68]; // [k][j], pad 68
    const int tid = threadIdx.x;
    const int c = tid & 15, a = tid >> 4;
    const int j0 = jblk * 64;
    const int ib = iblk * 64 + a * 4;
    const int k0 = sigma * 256;

    float acc[4][4];
#pragma unroll
    for (int ii = 0; ii < 4; ++ii)
#pragma unroll
        for (int jj = 0; jj < 4; ++jj) acc[ii][jj] = 0.f;

    for (int kt = 0; kt < 4; ++kt) {
        const int k1 = k0 + kt * 64;
#pragma unroll
        for (int stp = 0; stp < 4; ++stp) {
            int f4 = stp * 256 + tid;
            int jr = f4 >> 4, e4 = f4 & 15;
            float4 wv = *(const float4*)&W[(size_t)(j0 + jr) * Cn + k1 + e4 * 4];
            wl[e4 * 4 + 0][jr] = wv.x;
            wl[e4 * 4 + 1][jr] = wv.y;
            wl[e4 * 4 + 2][jr] = wv.z;
            wl[e4 * 4 + 3][jr] = wv.w;
        }
        __syncthreads();
#pragma unroll 4
        for (int k4 = 0; k4 < 16; ++k4) {
            float4 xv[4];
#pragma unroll
            for (int ii = 0; ii < 4; ++ii)
                xv[ii] = *(const float4*)&X[(size_t)(ib + ii) * Cn + k1 + k4 * 4];
#pragma unroll
            for (int kk = 0; kk < 4; ++kk) {
                float4 wv = *(const float4*)&wl[k4 * 4 + kk][c * 4];
#pragma unroll
                for (int ii = 0; ii < 4; ++ii) {
                    const float xs = (kk == 0) ? xv[ii].x : (kk == 1) ? xv[ii].y
                                   : (kk == 2) ? xv[ii].z : xv[ii].w;
                    acc[ii][0] += xs * wv.x;
                    acc[ii][1] += xs * wv.y;
                    acc[ii][2] += xs * wv.z;
                    acc[ii][3] += xs * wv.w;
                }
            }
        }
        __syncthreads();
    }
    float* op = Opart + (size_t)sigma * PROJ_PART;
#pragma unroll
    for (int ii = 0; ii < 4; ++ii) {
        float4 o = make_float4(acc[ii][0], acc[ii][1], acc[ii][2], acc[ii][3]);
        *(float4*)&op[(size_t)(ib + ii) * Cn + j0 + c * 4] = o;
    }
}

__global__ __launch_bounds__(256) void proj3_kernel(
    const float* __restrict__ X, const float* __restrict__ W0,
    const float* __restrict__ W1, const float* __restrict__ W2,
    float* __restrict__ O0, float* __restrict__ O1, float* __restrict__ O2) {
    const int z = blockIdx.z;
    const float* W = (z < 4) ? W0 : (z < 8 ? W1 : W2);
    float* O = (z < 4) ? O0 : (z < 8 ? O1 : O2);
    gemm_body(X, W, O, z & 3, blockIdx.x, blockIdx.y);
}

__global__ __launch_bounds__(256) void gemm1_kernel(
    const float* __restrict__ X, const float* __restrict__ W, float* __restrict__ O) {
    gemm_body(X, W, O, blockIdx.z, blockIdx.x, blockIdx.y);
}

// ---------------- Pre-reduce K-split partials -> q (scaled), k_new, v_new ------
__global__ __launch_bounds__(256) void prereduce_kernel(
    const float* __restrict__ qp, const float* __restrict__ kp,
    const float* __restrict__ vp, float* __restrict__ q,
    float* __restrict__ kn, float* __restrict__ vn) {
    const size_t i = ((size_t)blockIdx.x * 256 + threadIdx.x) * 4;
#define SUM4(P)                                                              \
    make_float4(                                                             \
        (*(const float4*)(P + i)).x + (*(const float4*)(P + PROJ_PART + i)).x + \
        (*(const float4*)(P + 2 * PROJ_PART + i)).x + (*(const float4*)(P + 3 * PROJ_PART + i)).x, \
        (*(const float4*)(P + i)).y + (*(const float4*)(P + PROJ_PART + i)).y + \
        (*(const float4*)(P + 2 * PROJ_PART + i)).y + (*(const float4*)(P + 3 * PROJ_PART + i)).y, \
        (*(const float4*)(P + i)).z + (*(const float4*)(P + PROJ_PART + i)).z + \
        (*(const float4*)(P + 2 * PROJ_PART + i)).z + (*(const float4*)(P + 3 * PROJ_PART + i)).z, \
        (*(const float4*)(P + i)).w + (*(const float4*)(P + PROJ_PART + i)).w + \
        (*(const float4*)(P + 2 * PROJ_PART + i)).w + (*(const float4*)(P + 3 * PROJ_PART + i)).w)
    float4 qv = SUM4(qp);
    qv.x *= SCALE; qv.y *= SCALE; qv.z *= SCALE; qv.w *= SCALE;
    *(float4*)&q[i] = qv;
    *(float4*)&kn[i] = SUM4(kp);
    *(float4*)&vn[i] = SUM4(vp);
#undef SUM4
}

// ---------------- Attention partials: head-quad blocks, full-row contiguity ----
// Grid (hq=4, CQ=64, b=32), 1 wave per block. Block covers 4 heads x 64 rows,
// processed as 4 subtiles of 16 rows. Every K/V load instruction reads a
// CONTIGUOUS 1KB (the 4-head 256-float slice of one row); an item's K and V
// regions are contiguous 64KB streams -> DRAM page locality (R10's 256B
// h-sliced reads hit each page 16x from drifting blocks; theory: that was the
// ~2x BW loss). Lane = (h4 = lane>>4, c4 = lane&15). QK: lane=(h4,row=c4),
// XOR-swizzled slots within each 16-slot quarter (bank-verified). PV:
// lane=(h4,d-quad=c4) -- V b128 row loads land in exactly the right lanes;
// per-lane-complete accumulators. Subtile pipeline: QK_s -> lgkmcnt(0) ->
// issue K_{s+1}/V_{s+1} (reg double-buffer, static A/B unroll) -> PV_s;
// counted vmcnt(16) at top. LDS 26KB -> 6 blocks/CU. (64,1) lifts VGPR cap
// (R5/R6 lesson: occupancy-targeting allocator spills big register arrays).
__global__ __launch_bounds__(64, 1) void attn_kernel(
    const float* __restrict__ q, const float* __restrict__ kn,
    const float* __restrict__ vn, const float* __restrict__ ck,
    const float* __restrict__ cv, const int* __restrict__ clen,
    float* __restrict__ pacc, float* __restrict__ pl) {
    const int hq = blockIdx.x, CQ = blockIdx.y, b = blockIdx.z;
    const int cl = clen[b];
    if (CQ != 0 && CQ * CHUNK >= cl) return; // uniform early exit

    const int lane = threadIdx.x;
    const int h4 = lane >> 4;  // head-in-quad
    const int c4 = lane & 15;  // row (QK) / d-quad (PV)

    __shared__ float K_l[16][256]; // 16 KB, swizzled quarters
    __shared__ float q_l[8][256];  // 8 KB, [t][4 heads x 64]
    __shared__ float p_l[8][64];   // 2 KB, [t][h4*16 + row]

    // max(cache_len)
    int mv = clen[lane & 31];
#pragma unroll
    for (int off = 16; off >= 1; off >>= 1) {
        int o = __shfl_xor(mv, off);
        mv = mv > o ? mv : o;
    }

    // stage q: 8 gload_lds, each a contiguous 1KB (one t, 4 heads)
    {
        const float* qb = q + (size_t)b * Tn * Cn + hq * 256;
#pragma unroll
        for (int t = 0; t < 8; ++t)
            gload_lds16(qb + (size_t)t * Cn + lane * 4, &q_l[t][0]);
    }
    __builtin_amdgcn_sched_barrier(0);

    const int nv = min(max(cl - CQ * CHUNK, 0), CHUNK);
    const int nst = (nv + 15) >> 4;

    const size_t kvbase = ((size_t)b * Sn + (size_t)CQ * CHUNK) * Cn + hq * 256;
    const float* kbase = ck + kvbase;
    const float* vbase = cv + kvbase;

    float av[8][4];
#pragma unroll
    for (int t = 0; t < 8; ++t) av[t][0] = av[t][1] = av[t][2] = av[t][3] = 0.f;
    float lden[8];
#pragma unroll
    for (int t = 0; t < 8; ++t) lden[t] = 0.f;

    // K subtile: 16 instrs, each reading one full 1KB row slice (pre-swizzled
    // source within each 16-slot quarter so the QK read is conflict-free)
    auto issueK = [&](int s) {
#pragma unroll
        for (int i = 0; i < 16; ++i) {
            const int sslot = (lane & 48) | ((lane & 15) ^ i);
            gload_lds16(kbase + (size_t)(s * 16 + i) * Cn + sslot * 4, &K_l[i][0]);
        }
    };
    // V subtile: 16 b128 instrs, 1KB contiguous each; lane gets exactly its
    // (h4, d-quad) floats of every row
    auto issueV = [&](int s, float4 (&vr)[16]) {
#pragma unroll
        for (int i = 0; i < 16; ++i)
            vr[i] = *(const float4*)(vbase + (size_t)(s * 16 + i) * Cn + lane * 4);
    };
    auto doQK = [&](int s) {
        float sc[8];
#pragma unroll
        for (int t = 0; t < 8; ++t) sc[t] = 0.f;
#pragma unroll
        for (int dg = 0; dg < 16; ++dg) {
            const float4 kv = *(const float4*)&K_l[c4][(h4 * 16 + (dg ^ c4)) * 4];
#pragma unroll
            for (int t = 0; t < 8; ++t) {
                const float4 qv = *(const float4*)&q_l[t][h4 * 64 + dg * 4];
                sc[t] += kv.x * qv.x + kv.y * qv.y + kv.z * qv.z + kv.w * qv.w;
            }
        }
        const bool val = (s * 16 + c4) < nv;
#pragma unroll
        for (int t = 0; t < 8; ++t) {
            const float p = val ? __expf(sc[t]) : 0.f;
            lden[t] += p;
            p_l[t][lane] = p;
        }
    };
    auto doPV = [&](float4 (&vr)[16]) {
#pragma unroll
        for (int r4 = 0; r4 < 4; ++r4) {
            float4 pt[8];
#pragma unroll
            for (int t = 0; t < 8; ++t) pt[t] = *(const float4*)&p_l[t][h4 * 16 + r4 * 4];
#pragma unroll
            for (int u = 0; u < 4; ++u) {
                const float4 vv = vr[r4 * 4 + u];
#pragma unroll
                for (int t = 0; t < 8; ++t) {
                    const float pu = (u == 0) ? pt[t].x : (u == 1) ? pt[t].y
                                   : (u == 2) ? pt[t].z : pt[t].w;
                    av[t][0] += pu * vv.x;
                    av[t][1] += pu * vv.y;
                    av[t][2] += pu * vv.z;
                    av[t][3] += pu * vv.w;
                }
            }
        }
    };

    if (nst > 0) {
        float4 vA[16], vB[16];
        issueK(0);
        __builtin_amdgcn_sched_barrier(0);
        issueV(0, vA);
        __builtin_amdgcn_sched_barrier(0);
        int s = 0;
        for (;;) {
            // ---- A phase
            asm volatile("s_waitcnt vmcnt(16)" ::: "memory"); // K_s (+q) resident
            __builtin_amdgcn_sched_barrier(0);
            doQK(s);
            asm volatile("s_waitcnt lgkmcnt(0)" ::: "memory"); // K_l reads drained
            __builtin_amdgcn_sched_barrier(0);
            if (s + 1 < nst) {
                issueK(s + 1);
                __builtin_amdgcn_sched_barrier(0);
                issueV(s + 1, vB);
                __builtin_amdgcn_sched_barrier(0);
            }
            doPV(vA);
            if (++s >= nst) break;
            // ---- B phase
            asm volatile("s_waitcnt vmcnt(16)" ::: "memory");
            __builtin_amdgcn_sched_barrier(0);
            doQK(s);
            asm volatile("s_waitcnt lgkmcnt(0)" ::: "memory");
            __builtin_amdgcn_sched_barrier(0);
            if (s + 1 < nst) {
                issueK(s + 1);
                __builtin_amdgcn_sched_barrier(0);
                issueV(s + 1, vA);
                __builtin_amdgcn_sched_barrier(0);
            }
            doPV(vB);
            if (++s >= nst) break;
        }
    }

    // ---- new keys (8 rows x this block's 4 heads): CQ==0 only
    if (CQ == 0) {
        if (lane < 32) { // lane = (hN = lane>>3, rN = lane&7)
            const int hN = lane >> 3, rN = lane & 7;
            const float* kb2 = kn + ((size_t)b * Tn + rN) * Cn + hq * 256 + hN * 64;
            float sd[8];
#pragma unroll
            for (int t = 0; t < 8; ++t) sd[t] = 0.f;
#pragma unroll
            for (int j = 0; j < 16; ++j) {
                const float4 kf = *(const float4*)(kb2 + j * 4);
#pragma unroll
                for (int t = 0; t < 8; ++t) {
                    const float4 qf = *(const float4*)&q_l[t][hN * 64 + j * 4];
                    sd[t] += kf.x * qf.x + kf.y * qf.y + kf.z * qf.z + kf.w * qf.w;
                }
            }
#pragma unroll
            for (int t = 0; t < 8; ++t) p_l[t][hN * 16 + rN] = __expf(sd[t]);
        }
        asm volatile("s_waitcnt lgkmcnt(0)" ::: "memory"); // cross-lane p_l visible
        __builtin_amdgcn_sched_barrier(0);
#pragma unroll
        for (int r4 = 0; r4 < 2; ++r4) {
            float4 pt[8];
#pragma unroll
            for (int t = 0; t < 8; ++t) pt[t] = *(const float4*)&p_l[t][h4 * 16 + r4 * 4];
#pragma unroll
            for (int u = 0; u < 4; ++u) {
                const int r = r4 * 4 + u;
                const float4 vv = *(const float4*)(vn + ((size_t)b * Tn + r) * Cn +
                                                   hq * 256 + h4 * 64 + c4 * 4);
#pragma unroll
                for (int t = 0; t < 8; ++t) {
                    const float pu = (u == 0) ? pt[t].x : (u == 1) ? pt[t].y
                                   : (u == 2) ? pt[t].z : pt[t].w;
                    av[t][0] += pu * vv.x;
                    av[t][1] += pu * vv.y;
                    av[t][2] += pu * vv.z;
                    av[t][3] += pu * vv.w;
                }
            }
        }
        if (c4 == 0) { // one lane per h-group folds new-key denoms + pad
#pragma unroll
            for (int t = 0; t < 8; ++t) {
                float ss = 0.f;
#pragma unroll
                for (int r = 0; r < 8; ++r) ss += p_l[t][h4 * 16 + r];
                lden[t] += ss + (float)(mv - cl);
            }
        }
    }

    // lden: butterfly within each 16-lane h-group (rows summed once)
#pragma unroll
    for (int t = 0; t < 8; ++t) {
        float v = lden[t];
        v += __shfl_xor(v, 1);
        v += __shfl_xor(v, 2);
        v += __shfl_xor(v, 4);
        v += __shfl_xor(v, 8);
        lden[t] = v;
    }

    const size_t obase = (size_t)((CQ * Bn + b) * Hn + hq * 4 + h4);
#pragma unroll
    for (int t = 0; t < 8; ++t)
        *(float4*)&pacc[obase * 512 + (size_t)t * 64 + c4 * 4] =
            make_float4(av[t][0], av[t][1], av[t][2], av[t][3]);
    if (c4 == 0) {
#pragma unroll
        for (int t = 0; t < 8; ++t) pl[obase * 8 + t] = lden[t];
    }
}

// ---------------- Merge chunk partials, normalize (4-wave) ----------------
__global__ __launch_bounds__(256) void attn_merge_kernel(
    const float* __restrict__ pacc, const float* __restrict__ pl,
    const int* __restrict__ clen, float* __restrict__ aw) {
    const int h = blockIdx.x, b = blockIdx.y;
    const int tid = threadIdx.x, wave = tid >> 6, lane = tid & 63;
    const int cl = clen[b];
    int nch = (cl + CHUNK - 1) / CHUNK;
    if (nch < 1) nch = 1;

    __shared__ float racc[4][8][64];
    __shared__ float rl[4][8];

    float acc[8], l[8];
#pragma unroll
    for (int t = 0; t < 8; ++t) { acc[t] = 0.f; l[t] = 0.f; }
    for (int c = wave; c < nch; c += 4) {
        const size_t base = (size_t)((c * Bn + b) * Hn + h);
#pragma unroll
        for (int t = 0; t < 8; ++t) acc[t] += pacc[base * 512 + t * 64 + lane];
#pragma unroll
        for (int t = 0; t < 8; ++t) l[t] += pl[base * 8 + t];
    }
#pragma unroll
    for (int t = 0; t < 8; ++t) racc[wave][t][lane] = acc[t];
    if (lane == 0) {
#pragma unroll
        for (int t = 0; t < 8; ++t) rl[wave][t] = l[t];
    }
    __syncthreads();
#pragma unroll
    for (int rep = 0; rep < 2; ++rep) {
        const int e = rep * 256 + tid;
        const int t = e >> 6, d = e & 63;
        const float a = racc[0][t][d] + racc[1][t][d] + racc[2][t][d] + racc[3][t][d];
        const float ll = rl[0][t] + rl[1][t] + rl[2][t] + rl[3][t];
        aw[(size_t)(b * Tn + t) * Cn + (size_t)h * HDn + d] = a / ll;
    }
}

// ---------------- Sum final-GEMM partials + bias ----------------
__global__ __launch_bounds__(256) void bias_out_kernel(
    const float* __restrict__ opart, const float* __restrict__ bo, float* __restrict__ out) {
    const int f4 = blockIdx.x * 256 + threadIdx.x; // 65536 float4s
    const float4 a0 = *(const float4*)(opart + (size_t)f4 * 4);
    const float4 a1 = *(const float4*)(opart + PROJ_PART + (size_t)f4 * 4);
    const float4 a2 = *(const float4*)(opart + 2 * PROJ_PART + (size_t)f4 * 4);
    const float4 a3 = *(const float4*)(opart + 3 * PROJ_PART + (size_t)f4 * 4);
    const float4 bv = *(const float4*)&bo[(f4 & 255) * 4];
    float4 o = make_float4(a0.x + a1.x + a2.x + a3.x + bv.x,
                           a0.y + a1.y + a2.y + a3.y + bv.y,
                           a0.z + a1.z + a2.z + a3.z + bv.z,
                           a0.w + a1.w + a2.w + a3.w + bv.w);
    *(float4*)&out[(size_t)f4 * 4] = o;
}

extern "C" void kernel_launch(void* const* d_in, const int* in_sizes, int n_in,
                              void* d_out, int out_size, void* d_ws, size_t ws_size,
                              hipStream_t stream) {
    const float* x  = (const float*)d_in[0];
    const float* ck = (const float*)d_in[1];
    const float* cv = (const float*)d_in[2];
    const int*   cl = (const int*)d_in[3];
    const float* wq = (const float*)d_in[4];
    const float* wk = (const float*)d_in[5];
    const float* wv = (const float*)d_in[6];
    const float* wo = (const float*)d_in[7];
    const float* bo = (const float*)d_in[8];
    float* out = (float*)d_out;
    float* ws = (float*)d_ws;

    float* qpart = ws + QP_OFF;
    float* kpart = ws + KP_OFF;
    float* vpart = ws + VP_OFF;
    float* pacc  = ws + PACC_OFF;
    float* pl    = ws + PL_OFF;
    float* aw    = ws + AW_OFF;
    float* opart = ws + OP_OFF;
    float* qr    = ws + QR_OFF;
    float* knew  = ws + KN_OFF;
    float* vnew  = ws + VN_OFF;

    // 1) q/k/v projections (K-split-4 partials)
    proj3_kernel<<<dim3(16, 4, 12), dim3(256), 0, stream>>>(x, wq, wk, wv, qpart, kpart, vpart);
    // 1b) reduce partials -> q (pre-scaled), k_new, v_new
    prereduce_kernel<<<dim3(256), dim3(256), 0, stream>>>(qpart, kpart, vpart, qr, knew, vnew);
    // 2) attention partials: head-quad 1-wave blocks, contiguous KV streams
    attn_kernel<<<dim3(4, NCHUNK, Bn), dim3(64), 0, stream>>>(qr, knew, vnew, ck, cv, cl, pacc, pl);
    // 3) merge + normalize (4-wave)
    attn_merge_kernel<<<dim3(Hn, Bn), dim3(256), 0, stream>>>(pacc, pl, cl, aw);
    // 4) output projection (K-split-4 partials)
    gemm1_kernel<<<dim3(16, 4, KSPLIT), dim3(256), 0, stream>>>(aw, wo, opart);
    // 5) sum partials + bias
    bias_out_kernel<<<dim3(256), dim3(256), 0, stream>>>(opart, bo, out);
}